// Round 11
// baseline (1115.951 us; speedup 1.0000x reference)
//
#include <hip/hip_runtime.h>
#include <hip/hip_cooperative_groups.h>
#include <stdint.h>

namespace cg = cooperative_groups;

#define AS1 __attribute__((address_space(1)))
#define AS3 __attribute__((address_space(3)))

typedef __bf16 bf16x8 __attribute__((ext_vector_type(8)));
typedef float f32x4 __attribute__((ext_vector_type(4)));

__device__ __forceinline__ float bf2f(unsigned short u) {
    return __uint_as_float(((unsigned)u) << 16);
}
__device__ __forceinline__ unsigned short f2bf(float f) {
    unsigned u = __float_as_uint(f);
    unsigned r = u + 0x7fffu + ((u >> 16) & 1u);  // RNE
    return (unsigned short)(r >> 16);
}
__device__ __forceinline__ void unpack4(uint2 u, float& a, float& b, float& c, float& d) {
    a = __uint_as_float(u.x << 16);
    b = __uint_as_float(u.x & 0xffff0000u);
    c = __uint_as_float(u.y << 16);
    d = __uint_as_float(u.y & 0xffff0000u);
}
__device__ __forceinline__ uint2 pack4(float a, float b, float c, float d) {
    uint2 o;
    o.x = (unsigned)f2bf(a) | ((unsigned)f2bf(b) << 16);
    o.y = (unsigned)f2bf(c) | ((unsigned)f2bf(d) << 16);
    return o;
}

// ==================== build kernel (cooperative): prep + CSR + xs + aggx ====================

struct BuildP {
    const float* x;
    const int* row;
    const int* col;
    const float* cw;
    const float* nw;
    const float* nb;
    unsigned short* cwT;
    unsigned short* w96;
    unsigned short* xs;
    unsigned short* hz;   // hws zero row (256)
    unsigned short* xz;   // xs zero row (64)
    int* zero_region;
    int zero_words;
    int* cnt;
    float* sdis;
    int* rowstart;
    int* scanbuf;
    int* bsum;
    int* boff;
    int* eidx;
    float* dis;
    unsigned short* y96;
    int N;
    int E;
    int nchunks;          // (N+255)/256, must be <= 256
};

__global__ __launch_bounds__(256, 4)
void build_kernel(BuildP p) {
    cg::grid_group grid = cg::this_grid();
    __shared__ int s_scan[256];
    __shared__ float s_colv[256];
    const int tid = threadIdx.x;
    const int gstride = gridDim.x * 256;

    // ---- P0: zero region, cwT transpose, pad rows, w96 fuse ----
    for (int i = blockIdx.x * 256 + tid; i < p.zero_words; i += gstride) p.zero_region[i] = 0;
    for (int idx = blockIdx.x * 256 + tid; idx < 3 * 256 * 256; idx += gstride) {
        int l = idx >> 16, rem = idx & 65535;
        int k = rem >> 8, n = rem & 255;
        p.cwT[(l << 16) + (n << 8) + k] = f2bf(p.cw[idx]);
    }
    if (blockIdx.x == gridDim.x - 1) {
        p.hz[tid] = 0;
        if (tid < 64) p.xz[tid] = 0;
    }
    for (int n = blockIdx.x; n < 256; n += gridDim.x) {
        s_colv[tid] = p.cw[tid * 256 + n];  // conv_w layer 0 column n
        __syncthreads();
        if (tid < 64) {
            float acc = 0.0f;
            for (int j = 0; j < 256; j++) acc += p.nw[tid * 256 + j] * s_colv[j];
            p.w96[n * 96 + tid] = f2bf(acc);
        } else if (tid == 64) {
            float acc = 0.0f;
            for (int j = 0; j < 256; j++) acc += p.nb[j] * s_colv[j];
            p.w96[n * 96 + tid] = f2bf(acc);
        } else if (tid < 96) {
            p.w96[n * 96 + tid] = 0;
        }
        __syncthreads();
    }
    grid.sync();

    // ---- P1: degree ----
    for (int e = blockIdx.x * 256 + tid; e < p.E; e += gstride) atomicAdd(&p.cnt[p.col[e]], 1);
    grid.sync();

    // ---- P2: per-chunk inclusive scan (256-wide) + dis ----
    for (int c = blockIdx.x; c < p.nchunks; c += gridDim.x) {
        int i = c * 256 + tid;
        int v = (i < p.N) ? p.cnt[i] : 0;
        if (i < p.N) p.dis[i] = rsqrtf((float)v + 1.0f);  // +1 self-loop
        s_scan[tid] = v;
        __syncthreads();
        for (int off = 1; off < 256; off <<= 1) {
            int t = (tid >= off) ? s_scan[tid - off] : 0;
            __syncthreads();
            s_scan[tid] += t;
            __syncthreads();
        }
        if (i < p.N) p.scanbuf[i] = s_scan[tid];
        if (tid == 255) p.bsum[c] = s_scan[255];
        __syncthreads();
    }
    grid.sync();

    // ---- P3: scan of chunk sums (block 0; nchunks <= 256) ----
    if (blockIdx.x == 0) {
        int v = (tid < p.nchunks) ? p.bsum[tid] : 0;
        s_scan[tid] = v;
        __syncthreads();
        for (int off = 1; off < 256; off <<= 1) {
            int t = (tid >= off) ? s_scan[tid - off] : 0;
            __syncthreads();
            s_scan[tid] += t;
            __syncthreads();
        }
        if (tid < p.nchunks) p.boff[tid] = s_scan[tid] - v;  // exclusive
    }
    grid.sync();

    // ---- P4: rowstart ----
    for (int i = blockIdx.x * 256 + tid; i < p.N; i += gstride)
        p.rowstart[i + 1] = p.scanbuf[i] + p.boff[i >> 8];
    if (blockIdx.x == 0 && tid == 0) p.rowstart[0] = 0;
    grid.sync();

    // ---- P5: scatter (atomicSub on warm cnt) + sdis + xs ----
    for (int e = blockIdx.x * 256 + tid; e < p.E; e += gstride) {
        int c = p.col[e];
        int r = p.row[e];
        int old = atomicSub(&p.cnt[c], 1);
        p.eidx[p.rowstart[c] + old - 1] = r;
        atomicAdd(&p.sdis[c], p.dis[r]);
    }
    int total4 = p.N * 16;  // N*64/4
    for (int i4 = blockIdx.x * 256 + tid; i4 < total4; i4 += gstride) {
        int i = i4 * 4;
        float d = p.dis[i >> 6];
        float4 v = *reinterpret_cast<const float4*>(p.x + i);
        *reinterpret_cast<uint2*>(p.xs + i) = pack4(d * v.x, d * v.y, d * v.z, d * v.w);
    }
    grid.sync();

    // ---- P6: aggx (layer-1 aggregation over xs -> y96), grid-stride groups ----
    {
        const int lane = tid & 63;
        const int wave = tid >> 6;
        const int slot = lane >> 3;
        const int fl = (lane & 7) * 8;
        const int N = p.N;
        const unsigned short* xs = p.xs;
        const int ngroups = (N + 15) / 16;
        for (int gidx = blockIdx.x; gidx < ngroups; gidx += gridDim.x) {
            const int vb = __builtin_amdgcn_readfirstlane(gidx * 16 + wave * 4);
            int rs[5];
#pragma unroll
            for (int s = 0; s < 5; s++) rs[s] = p.rowstart[min(vb + s, N)];
            int js[4], de[4];
            float dvv[4], svv[4];
#pragma unroll
            for (int s = 0; s < 4; s++) {
                js[s] = rs[s];
                bool ok = (vb + s) < N;
                de[s] = ok ? (rs[s + 1] - rs[s]) : 0;
                float dv = ok ? p.dis[vb + s] : 0.0f;
                dvv[s] = dv;
                svv[s] = ok ? (dv * (dv + p.sdis[vb + s])) : 0.0f;
            }
            int idx0 = (lane < de[0]) ? p.eidx[js[0] + lane] : N;
            int idx1 = (lane < de[1]) ? p.eidx[js[1] + lane] : N;
            int idx2 = (lane < de[2]) ? p.eidx[js[2] + lane] : N;
            int idx3 = (lane < de[3]) ? p.eidx[js[3] + lane] : N;
            uint4 sf[4];
#pragma unroll
            for (int s = 0; s < 4; s++)
                sf[s] = *reinterpret_cast<const uint4*>(xs + (size_t)min(vb + s, N) * 64 + fl);

            uint4 rA[2], rB[2], rC[2];
            auto issue = [&](int myidx, uint4 (&rr)[2]) {
#pragma unroll
                for (int ro = 0; ro < 2; ro++) {
                    int u = __shfl(myidx, ro * 8 + slot);
                    rr[ro] = *reinterpret_cast<const uint4*>(xs + (size_t)u * 64 + fl);
                }
            };
            auto consume = [&](int s, int js_s, int d, float dv, float sv, int myidx,
                               uint4 (&rr)[2]) {
                float a[8] = {};
#pragma unroll
                for (int ro = 0; ro < 2; ro++) {
                    float x0, x1, x2, x3;
                    unpack4(make_uint2(rr[ro].x, rr[ro].y), x0, x1, x2, x3);
                    a[0] += x0; a[1] += x1; a[2] += x2; a[3] += x3;
                    unpack4(make_uint2(rr[ro].z, rr[ro].w), x0, x1, x2, x3);
                    a[4] += x0; a[5] += x1; a[6] += x2; a[7] += x3;
                }
                int cnp = min(64, (d + 15) & ~15);
                for (int t = 16; t < cnp; t += 16) {
#pragma unroll
                    for (int ro = 0; ro < 2; ro++) {
                        int u = __shfl(myidx, t + ro * 8 + slot);
                        rr[ro] = *reinterpret_cast<const uint4*>(xs + (size_t)u * 64 + fl);
                    }
#pragma unroll
                    for (int ro = 0; ro < 2; ro++) {
                        float x0, x1, x2, x3;
                        unpack4(make_uint2(rr[ro].x, rr[ro].y), x0, x1, x2, x3);
                        a[0] += x0; a[1] += x1; a[2] += x2; a[3] += x3;
                        unpack4(make_uint2(rr[ro].z, rr[ro].w), x0, x1, x2, x3);
                        a[4] += x0; a[5] += x1; a[6] += x2; a[7] += x3;
                    }
                }
                for (int base = 64; base < d; base += 64) {
                    int mi = (base + lane < d) ? p.eidx[js_s + base + lane] : N;
                    int cn2 = min(64, d - base);
                    int cnp2 = (cn2 + 15) & ~15;
                    for (int t = 0; t < cnp2; t += 16) {
#pragma unroll
                        for (int ro = 0; ro < 2; ro++) {
                            int u = __shfl(mi, t + ro * 8 + slot);
                            rr[ro] = *reinterpret_cast<const uint4*>(xs + (size_t)u * 64 + fl);
                        }
#pragma unroll
                        for (int ro = 0; ro < 2; ro++) {
                            float x0, x1, x2, x3;
                            unpack4(make_uint2(rr[ro].x, rr[ro].y), x0, x1, x2, x3);
                            a[0] += x0; a[1] += x1; a[2] += x2; a[3] += x3;
                            unpack4(make_uint2(rr[ro].z, rr[ro].w), x0, x1, x2, x3);
                            a[4] += x0; a[5] += x1; a[6] += x2; a[7] += x3;
                        }
                    }
                }
#pragma unroll
                for (int j = 0; j < 8; j++) {
                    a[j] += __shfl_xor(a[j], 8);
                    a[j] += __shfl_xor(a[j], 16);
                    a[j] += __shfl_xor(a[j], 32);
                }
                if ((vb + s) < N) {
                    if (lane < 8) {
                        float x0, x1, x2, x3;
                        unpack4(make_uint2(sf[s].x, sf[s].y), x0, x1, x2, x3);
                        a[0] += x0; a[1] += x1; a[2] += x2; a[3] += x3;
                        unpack4(make_uint2(sf[s].z, sf[s].w), x0, x1, x2, x3);
                        a[4] += x0; a[5] += x1; a[6] += x2; a[7] += x3;
                        uint2 lo = pack4(dv * a[0], dv * a[1], dv * a[2], dv * a[3]);
                        uint2 hi = pack4(dv * a[4], dv * a[5], dv * a[6], dv * a[7]);
                        *reinterpret_cast<uint4*>(p.y96 + (size_t)(vb + s) * 96 + fl) =
                            make_uint4(lo.x, lo.y, hi.x, hi.y);
                    } else if (lane < 12) {
                        unsigned sx = (lane == 8) ? (unsigned)f2bf(sv) : 0u;
                        *reinterpret_cast<uint4*>(p.y96 + (size_t)(vb + s) * 96 + 64 +
                                                  (lane - 8) * 8) = make_uint4(sx, 0u, 0u, 0u);
                    }
                }
            };
            issue(idx0, rA);
            issue(idx1, rB);
            issue(idx2, rC);
            consume(0, js[0], de[0], dvv[0], svv[0], idx0, rA);
            issue(idx3, rA);
            consume(1, js[1], de[1], dvv[1], svv[1], idx1, rB);
            consume(2, js[2], de[2], dvv[2], svv[2], idx2, rC);
            consume(3, js[3], de[3], dvv[3], svv[3], idx3, rA);
        }
    }
}

// ==================== mega kernel (cooperative): all 3 layers + pool + head ====================

struct MegaP {
    const unsigned short* y96;
    const unsigned short* w96;
    const unsigned short* cwT;
    unsigned short* h;
    unsigned short* hws;
    unsigned short* agg;
    float* stats;
    const float* dis;
    const int* rowstart;
    const int* eidx;
    const float* bn_g;
    const float* bn_b;
    const int* batch;
    float* gpool;
    const float* hw1;
    const float* hb1;
    const float* hw2;
    const float* hb2;
    float* out;
    int N;
    int mtiles;
    float inv_n;
};

__device__ __forceinline__ void gemm_phase(char* SMEM, const unsigned short* __restrict__ A,
                                           const unsigned short* __restrict__ BT,
                                           unsigned short* __restrict__ C,
                                           const float* __restrict__ scale,
                                           float* __restrict__ stats_accum,
                                           int M, int K, int mtiles) {
    unsigned short* As = (unsigned short*)SMEM;
    unsigned short* Bs = (unsigned short*)(SMEM + 8192);
    float* stLS = (float*)(SMEM + 16384);
    const int lane = threadIdx.x & 63;
    const int wave = threadIdx.x >> 6;
    const int wm = wave >> 1, wn = wave & 1;
    const int r = lane & 15, q = lane >> 4;
    const int ntiles = mtiles * 2;
    const int Nc = 256;

    for (int T = blockIdx.x; T < ntiles; T += gridDim.x) {
        const int m0b = (T >> 1) * 128;
        const int n0b = (T & 1) * 128;
        const int m0 = m0b + wm * 64;
        const int n0 = n0b + wn * 64;
        if (stats_accum) stLS[threadIdx.x] = 0.0f;

        f32x4 acc[4][4] = {};
        for (int k0 = 0; k0 < K; k0 += 32) {
            __syncthreads();
#pragma unroll
            for (int j = 0; j < 2; j++) {
                int s = threadIdx.x + j * 256;
                int rw = s >> 2, kp = s & 3;
                int mr = m0b + rw;
                if (mr >= M) mr = M - 1;
                const unsigned short* ga = A + (size_t)mr * K + k0 + kp * 8;
                __builtin_amdgcn_global_load_lds((const AS1 void*)ga, (AS3 void*)(As + s * 8),
                                                 16, 0, 0);
                int nr = n0b + rw;
                const unsigned short* gb = BT + (size_t)nr * K + k0 + kp * 8;
                __builtin_amdgcn_global_load_lds((const AS1 void*)gb, (AS3 void*)(Bs + s * 8),
                                                 16, 0, 0);
            }
            __syncthreads();

            bf16x8 a[4], b[4];
#pragma unroll
            for (int i = 0; i < 4; i++)
                a[i] = *reinterpret_cast<const bf16x8*>(As + ((wm * 64 + i * 16 + r) * 32 + q * 8));
#pragma unroll
            for (int j = 0; j < 4; j++)
                b[j] = *reinterpret_cast<const bf16x8*>(Bs + ((wn * 64 + j * 16 + r) * 32 + q * 8));
#pragma unroll
            for (int i = 0; i < 4; i++)
#pragma unroll
                for (int j = 0; j < 4; j++)
                    acc[i][j] = __builtin_amdgcn_mfma_f32_16x16x32_bf16(a[i], b[j], acc[i][j],
                                                                        0, 0, 0);
        }

        float psl[4] = {}, pql[4] = {};
#pragma unroll
        for (int i = 0; i < 4; i++) {
#pragma unroll
            for (int t = 0; t < 4; t++) {
                int mr = m0 + i * 16 + q * 4 + t;
                if (mr < M) {
                    float rs = scale ? scale[mr] : 1.0f;
#pragma unroll
                    for (int j = 0; j < 4; j++) {
                        int nc = n0 + j * 16 + r;
                        float v = acc[i][j][t] * rs;
                        C[(size_t)mr * Nc + nc] = f2bf(v);
                        psl[j] += v;
                        pql[j] += v * v;
                    }
                }
            }
        }

        if (stats_accum) {
            __syncthreads();
#pragma unroll
            for (int j = 0; j < 4; j++) {
                int c = wn * 64 + j * 16 + r;
                atomicAdd(&stLS[c], psl[j]);
                atomicAdd(&stLS[128 + c], pql[j]);
            }
            __syncthreads();
            if (threadIdx.x < 128) {
                atomicAdd(&stats_accum[n0b + threadIdx.x], stLS[threadIdx.x]);
                atomicAdd(&stats_accum[256 + n0b + threadIdx.x], stLS[128 + threadIdx.x]);
            }
            __syncthreads();
        }
    }
}

__device__ __forceinline__ void agg_phase(char* SMEM, const unsigned short* __restrict__ hws,
                                          const int* __restrict__ rowstart,
                                          const int* __restrict__ eidx,
                                          const float* __restrict__ dis,
                                          unsigned short* __restrict__ aggo,
                                          float* __restrict__ stats, int N) {
    float* s_sum = (float*)SMEM;             // [4][256]
    float* s_sq = (float*)(SMEM + 4096);
    const int lane = threadIdx.x & 63;
    const int wave = threadIdx.x >> 6;
    const int sub = lane >> 5;
    const int fl = (lane & 31) * 8;
    float ps[8] = {}, pq[8] = {};
    const int ngroups = (N + 15) / 16;

    for (int gidx = blockIdx.x; gidx < ngroups; gidx += gridDim.x) {
        const int vb = __builtin_amdgcn_readfirstlane(gidx * 16 + wave * 4);
        int rs[5];
#pragma unroll
        for (int s = 0; s < 5; s++) rs[s] = rowstart[min(vb + s, N)];
        int js[4], de[4];
        float dvv[4];
#pragma unroll
        for (int s = 0; s < 4; s++) {
            js[s] = rs[s];
            de[s] = (vb + s < N) ? (rs[s + 1] - rs[s]) : 0;
            dvv[s] = (vb + s < N) ? dis[vb + s] : 0.0f;
        }
        int idx0 = (lane < de[0]) ? eidx[js[0] + lane] : N;
        int idx1 = (lane < de[1]) ? eidx[js[1] + lane] : N;
        int idx2 = (lane < de[2]) ? eidx[js[2] + lane] : N;
        int idx3 = (lane < de[3]) ? eidx[js[3] + lane] : N;
        uint4 sf[4];
#pragma unroll
        for (int s = 0; s < 4; s++)
            sf[s] = *reinterpret_cast<const uint4*>(hws + (size_t)min(vb + s, N) * 256 + fl);

        uint4 rA[8], rB[8];
        auto issue = [&](int myidx, uint4 (&rr)[8]) {
#pragma unroll
            for (int k = 0; k < 8; k++) {
                int u = __shfl(myidx, 2 * k + sub);
                rr[k] = *reinterpret_cast<const uint4*>(hws + (size_t)u * 256 + fl);
            }
        };
        auto consume = [&](int s, int js_s, int d, float dvs, int myidx, uint4 (&rr)[8]) {
            float a[8] = {};
#pragma unroll
            for (int k = 0; k < 8; k++) {
                float x0, x1, x2, x3;
                unpack4(make_uint2(rr[k].x, rr[k].y), x0, x1, x2, x3);
                a[0] += x0; a[1] += x1; a[2] += x2; a[3] += x3;
                unpack4(make_uint2(rr[k].z, rr[k].w), x0, x1, x2, x3);
                a[4] += x0; a[5] += x1; a[6] += x2; a[7] += x3;
            }
            int cnp = min(64, (d + 15) & ~15);
            for (int t = 16; t < cnp; t += 16) {
#pragma unroll
                for (int k = 0; k < 8; k++) {
                    int u = __shfl(myidx, t + 2 * k + sub);
                    rr[k] = *reinterpret_cast<const uint4*>(hws + (size_t)u * 256 + fl);
                }
#pragma unroll
                for (int k = 0; k < 8; k++) {
                    float x0, x1, x2, x3;
                    unpack4(make_uint2(rr[k].x, rr[k].y), x0, x1, x2, x3);
                    a[0] += x0; a[1] += x1; a[2] += x2; a[3] += x3;
                    unpack4(make_uint2(rr[k].z, rr[k].w), x0, x1, x2, x3);
                    a[4] += x0; a[5] += x1; a[6] += x2; a[7] += x3;
                }
            }
            for (int base = 64; base < d; base += 64) {
                int mi = (base + lane < d) ? eidx[js_s + base + lane] : N;
                int cn2 = min(64, d - base);
                int cnp2 = (cn2 + 15) & ~15;
                for (int t = 0; t < cnp2; t += 16) {
#pragma unroll
                    for (int k = 0; k < 8; k++) {
                        int u = __shfl(mi, t + 2 * k + sub);
                        rr[k] = *reinterpret_cast<const uint4*>(hws + (size_t)u * 256 + fl);
                    }
#pragma unroll
                    for (int k = 0; k < 8; k++) {
                        float x0, x1, x2, x3;
                        unpack4(make_uint2(rr[k].x, rr[k].y), x0, x1, x2, x3);
                        a[0] += x0; a[1] += x1; a[2] += x2; a[3] += x3;
                        unpack4(make_uint2(rr[k].z, rr[k].w), x0, x1, x2, x3);
                        a[4] += x0; a[5] += x1; a[6] += x2; a[7] += x3;
                    }
                }
            }
#pragma unroll
            for (int j = 0; j < 8; j++) a[j] += __shfl_xor(a[j], 32);
            float x0, x1, x2, x3;
            unpack4(make_uint2(sf[s].x, sf[s].y), x0, x1, x2, x3);
            a[0] += x0; a[1] += x1; a[2] += x2; a[3] += x3;
            unpack4(make_uint2(sf[s].z, sf[s].w), x0, x1, x2, x3);
            a[4] += x0; a[5] += x1; a[6] += x2; a[7] += x3;
            float g[8];
#pragma unroll
            for (int j = 0; j < 8; j++) g[j] = dvs * a[j];
            if (vb + s < N && sub == 0) {
                uint2 lo = pack4(g[0], g[1], g[2], g[3]);
                uint2 hi = pack4(g[4], g[5], g[6], g[7]);
                *reinterpret_cast<uint4*>(aggo + (size_t)(vb + s) * 256 + fl) =
                    make_uint4(lo.x, lo.y, hi.x, hi.y);
#pragma unroll
                for (int j = 0; j < 8; j++) { ps[j] += g[j]; pq[j] += g[j] * g[j]; }
            }
        };
        issue(idx0, rA);
        issue(idx1, rB);
        consume(0, js[0], de[0], dvv[0], idx0, rA);
        issue(idx2, rA);
        consume(1, js[1], de[1], dvv[1], idx1, rB);
        issue(idx3, rB);
        consume(2, js[2], de[2], dvv[2], idx2, rA);
        consume(3, js[3], de[3], dvv[3], idx3, rB);
    }

    if (sub == 0) {
#pragma unroll
        for (int j = 0; j < 8; j++) {
            s_sum[wave * 256 + fl + j] = ps[j];
            s_sq[wave * 256 + fl + j] = pq[j];
        }
    }
    __syncthreads();
    int f = threadIdx.x;
    float ts = s_sum[f] + s_sum[256 + f] + s_sum[512 + f] + s_sum[768 + f];
    float tq = s_sq[f] + s_sq[256 + f] + s_sq[512 + f] + s_sq[768 + f];
    atomicAdd(&stats[f], ts);
    atomicAdd(&stats[256 + f], tq);
}

__device__ __forceinline__ void elem_phase(char* SMEM, const unsigned short* __restrict__ aggi,
                                           const float* __restrict__ stats,
                                           const float* __restrict__ bng,
                                           const float* __restrict__ bnb,
                                           unsigned short* __restrict__ h, float inv_n, int N) {
    float* ssL = (float*)SMEM;
    int f = threadIdx.x;
    {
        float mean = stats[f] * inv_n;
        float var = stats[256 + f] * inv_n - mean * mean;
        float sc = bng[f] * rsqrtf(var + 1e-5f);
        ssL[f] = sc;
        ssL[256 + f] = bnb[f] - mean * sc;
    }
    __syncthreads();
    size_t total4 = (size_t)N * 64;
    for (size_t i4 = (size_t)blockIdx.x * 256 + f; i4 < total4; i4 += (size_t)gridDim.x * 256) {
        size_t i = i4 * 4;
        float a0, a1, a2, a3;
        unpack4(*reinterpret_cast<const uint2*>(aggi + i), a0, a1, a2, a3);
        int ff = (int)(i & 255);
        float r0 = fmaxf(a0 * ssL[ff] + ssL[256 + ff], 0.0f);
        float r1 = fmaxf(a1 * ssL[ff + 1] + ssL[256 + ff + 1], 0.0f);
        float r2 = fmaxf(a2 * ssL[ff + 2] + ssL[256 + ff + 2], 0.0f);
        float r3 = fmaxf(a3 * ssL[ff + 3] + ssL[256 + ff + 3], 0.0f);
        *reinterpret_cast<uint2*>(h + i) = pack4(r0, r1, r2, r3);
    }
}

__device__ __forceinline__ void elem_pool_phase(char* SMEM,
                                                const unsigned short* __restrict__ aggi,
                                                const float* __restrict__ stats,
                                                const float* __restrict__ bng,
                                                const float* __restrict__ bnb,
                                                const int* __restrict__ batch,
                                                float* __restrict__ g, float inv_n, int N) {
    float* ssL = (float*)SMEM;
    int* sb = (int*)(SMEM + 2048);
    int f = threadIdx.x;
    {
        float mean = stats[f] * inv_n;
        float var = stats[256 + f] * inv_n - mean * mean;
        float sc = bng[f] * rsqrtf(var + 1e-5f);
        ssL[f] = sc;
        ssL[256 + f] = bnb[f] - mean * sc;
    }
    __syncthreads();
    float sc = ssL[f], sh = ssL[256 + f];
    int nch = (N + 31) / 32;
    for (int c = blockIdx.x; c < nch; c += gridDim.x) {
        __syncthreads();
        int r0 = c * 32;
        int rows = min(32, N - r0);
        if (f < 32) sb[f] = (r0 + f < N) ? batch[r0 + f] : -1;
        __syncthreads();
        float acc = 0.0f;
        int cur = sb[0];
        for (int t = 0; t < rows; t++) {
            int b = sb[t];
            if (b != cur) {
                atomicAdd(&g[cur * 256 + f], acc);
                acc = 0.0f;
                cur = b;
            }
            float v = bf2f(aggi[(size_t)(r0 + t) * 256 + f]);
            acc += fmaxf(v * sc + sh, 0.0f);
        }
        atomicAdd(&g[cur * 256 + f], acc);
    }
}

__global__ __launch_bounds__(256, 3)
void mega_kernel(MegaP p) {
    cg::grid_group grid = cg::this_grid();
    __shared__ char SMEM[17408];

    // P0: layer-1 GEMM (y96 @ w96 -> agg) with fused BN-stats accumulation
    gemm_phase(SMEM, p.y96, p.w96, p.agg, nullptr, p.stats, p.N, 96, p.mtiles);
    grid.sync();
    // P1: elem1 (BN+ReLU -> h)
    elem_phase(SMEM, p.agg, p.stats, p.bn_g, p.bn_b, p.h, p.inv_n, p.N);
    grid.sync();
    // P2: clear stats; gemm2 (h @ cwT1 -> hws, pre-scaled by dis)
    if (blockIdx.x == 0) {
        p.stats[threadIdx.x] = 0.0f;
        p.stats[256 + threadIdx.x] = 0.0f;
    }
    gemm_phase(SMEM, p.h, p.cwT + 65536, p.hws, p.dis, nullptr, p.N, 256, p.mtiles);
    grid.sync();
    // P3: agg2
    agg_phase(SMEM, p.hws, p.rowstart, p.eidx, p.dis, p.agg, p.stats, p.N);
    grid.sync();
    // P4: elem2
    elem_phase(SMEM, p.agg, p.stats, p.bn_g + 256, p.bn_b + 256, p.h, p.inv_n, p.N);
    grid.sync();
    // P5: clear stats; gemm3
    if (blockIdx.x == 0) {
        p.stats[threadIdx.x] = 0.0f;
        p.stats[256 + threadIdx.x] = 0.0f;
    }
    gemm_phase(SMEM, p.h, p.cwT + 131072, p.hws, p.dis, nullptr, p.N, 256, p.mtiles);
    grid.sync();
    // P6: agg3
    agg_phase(SMEM, p.hws, p.rowstart, p.eidx, p.dis, p.agg, p.stats, p.N);
    grid.sync();
    // P7: elem_pool (BN+ReLU fused into global_add_pool; h never written)
    elem_pool_phase(SMEM, p.agg, p.stats, p.bn_g + 512, p.bn_b + 512, p.batch, p.gpool,
                    p.inv_n, p.N);
    grid.sync();
    // P8: head MLP (blocks 0..63)
    if (blockIdx.x < 64) {
        float* gr = (float*)SMEM;
        float* z = gr + 256;
        int b = blockIdx.x, t = threadIdx.x;
        gr[t] = p.gpool[b * 256 + t];
        __syncthreads();
        if (t < 128) {
            float acc = p.hb1[t];
            for (int k = 0; k < 256; k++) acc += gr[k] * p.hw1[k * 128 + t];
            z[t] = fmaxf(acc, 0.0f);
        }
        __syncthreads();
        if (t < 12) {
            float o = p.hb2[t];
            for (int k = 0; k < 128; k++) o += z[k] * p.hw2[k * 12 + t];
            p.out[b * 12 + t] = o;
        }
    }
}

// ==================== launch ====================

extern "C" void kernel_launch(void* const* d_in, const int* in_sizes, int n_in,
                              void* d_out, int out_size, void* d_ws, size_t ws_size,
                              hipStream_t stream) {
    const float* x      = (const float*)d_in[0];
    const int*   ei     = (const int*)d_in[1];
    const int*   batch  = (const int*)d_in[2];
    const float* node_w = (const float*)d_in[3];
    const float* node_b = (const float*)d_in[4];
    const float* conv_w = (const float*)d_in[5];
    const float* bn_g   = (const float*)d_in[7];
    const float* bn_b   = (const float*)d_in[8];
    const float* hw1    = (const float*)d_in[9];
    const float* hb1    = (const float*)d_in[10];
    const float* hw2    = (const float*)d_in[11];
    const float* hb2    = (const float*)d_in[12];
    float* out = (float*)d_out;

    const int N = in_sizes[2];
    const int E = in_sizes[1] / 2;
    const int H = 256;

    char* base = (char*)d_ws;
    size_t off = 0;
    auto alloc = [&](size_t bytes) -> void* {
        off = (off + 255) & ~(size_t)255;
        void* p = base + off;
        off += bytes;
        return p;
    };
    unsigned short* xs  = (unsigned short*)alloc((size_t)(N + 1) * 64 * 2);
    unsigned short* y96 = (unsigned short*)alloc((size_t)N * 96 * 2);
    unsigned short* w96 = (unsigned short*)alloc((size_t)256 * 96 * 2);
    unsigned short* h   = (unsigned short*)alloc((size_t)N * H * 2);
    unsigned short* hws = (unsigned short*)alloc((size_t)(N + 1) * H * 2);
    unsigned short* agg = (unsigned short*)alloc((size_t)N * H * 2);
    unsigned short* cwT = (unsigned short*)alloc((size_t)3 * H * H * 2);
    int zero_words = 2 * N + 512 + 64 * H;
    int* zero_region = (int*)alloc((size_t)zero_words * 4);
    int* cnt      = zero_region;
    float* sdis   = (float*)(zero_region + N);
    float* stats  = (float*)(zero_region + 2 * N);
    float* gpool  = (float*)(zero_region + 2 * N + 512);
    int* rowstart = (int*)alloc((size_t)(N + 1) * 4);
    int* scanbuf  = (int*)alloc((size_t)N * 4);
    int* bsum     = (int*)alloc(1024);
    int* boff     = (int*)alloc(1024);
    int* eidx     = (int*)alloc((size_t)(E + 64) * 4);
    float* dis    = (float*)alloc((size_t)N * 4);

    int maxb_build = 0, maxb_mega = 0;
    hipOccupancyMaxActiveBlocksPerMultiprocessor(&maxb_build, build_kernel, 256, 0);
    hipOccupancyMaxActiveBlocksPerMultiprocessor(&maxb_mega, mega_kernel, 256, 0);
    int gb = maxb_build * 256;  // 256 CUs
    int gm = maxb_mega * 256;
    if (gb < 256) gb = 256;
    if (gb > 2048) gb = 2048;
    if (gm < 256) gm = 256;
    if (gm > 2048) gm = 2048;

    BuildP bp;
    bp.x = x; bp.row = ei; bp.col = ei + E;
    bp.cw = conv_w; bp.nw = node_w; bp.nb = node_b;
    bp.cwT = cwT; bp.w96 = w96; bp.xs = xs;
    bp.hz = hws + (size_t)N * H; bp.xz = xs + (size_t)N * 64;
    bp.zero_region = zero_region; bp.zero_words = zero_words;
    bp.cnt = cnt; bp.sdis = sdis;
    bp.rowstart = rowstart; bp.scanbuf = scanbuf; bp.bsum = bsum; bp.boff = boff;
    bp.eidx = eidx; bp.dis = dis; bp.y96 = y96;
    bp.N = N; bp.E = E; bp.nchunks = (N + 255) / 256;

    MegaP mp;
    mp.y96 = y96; mp.w96 = w96; mp.cwT = cwT;
    mp.h = h; mp.hws = hws; mp.agg = agg;
    mp.stats = stats; mp.dis = dis; mp.rowstart = rowstart; mp.eidx = eidx;
    mp.bn_g = bn_g; mp.bn_b = bn_b; mp.batch = batch; mp.gpool = gpool;
    mp.hw1 = hw1; mp.hb1 = hb1; mp.hw2 = hw2; mp.hb2 = hb2; mp.out = out;
    mp.N = N; mp.mtiles = (N + 127) / 128; mp.inv_n = 1.0f / (float)N;

    void* bargs[] = {&bp};
    hipLaunchCooperativeKernel((void*)build_kernel, dim3(gb), dim3(256), bargs, 0, stream);
    void* margs[] = {&mp};
    hipLaunchCooperativeKernel((void*)mega_kernel, dim3(gm), dim3(256), margs, 0, stream);
}

// Round 12
// 512.401 us; speedup vs baseline: 2.1779x; 2.1779x over previous
//
#include <hip/hip_runtime.h>
#include <stdint.h>

#define AS1 __attribute__((address_space(1)))
#define AS3 __attribute__((address_space(3)))

typedef __bf16 bf16x8 __attribute__((ext_vector_type(8)));
typedef float f32x4 __attribute__((ext_vector_type(4)));

__device__ __forceinline__ float bf2f(unsigned short u) {
    return __uint_as_float(((unsigned)u) << 16);
}
__device__ __forceinline__ unsigned short f2bf(float f) {
    unsigned u = __float_as_uint(f);
    unsigned r = u + 0x7fffu + ((u >> 16) & 1u);  // RNE
    return (unsigned short)(r >> 16);
}
__device__ __forceinline__ void unpack4(uint2 u, float& a, float& b, float& c, float& d) {
    a = __uint_as_float(u.x << 16);
    b = __uint_as_float(u.x & 0xffff0000u);
    c = __uint_as_float(u.y << 16);
    d = __uint_as_float(u.y & 0xffff0000u);
}
__device__ __forceinline__ uint2 pack4(float a, float b, float c, float d) {
    uint2 o;
    o.x = (unsigned)f2bf(a) | ((unsigned)f2bf(b) << 16);
    o.y = (unsigned)f2bf(c) | ((unsigned)f2bf(d) << 16);
    return o;
}

// ---------------- prep: cwT transpose | zero pad rows | wfuse, one packed grid ----------------
// blocks [0,768): cwT; block 768: zero rows; blocks [769,1025): wfuse column n = b-769.

__global__ void prep_kernel(const float* __restrict__ cw, unsigned short* __restrict__ cwT,
                            unsigned short* __restrict__ hz, unsigned short* __restrict__ xz,
                            const float* __restrict__ nw, const float* __restrict__ nb,
                            unsigned short* __restrict__ w96) {
    __shared__ float colv[256];
    int b = blockIdx.x, t = threadIdx.x;
    if (b < 768) {
        int idx = b * 256 + t;  // over 3*256*256
        int l = idx >> 16, rem = idx & 65535;
        int k = rem >> 8, n = rem & 255;
        cwT[(l << 16) + (n << 8) + k] = f2bf(cw[idx]);
    } else if (b == 768) {
        hz[t] = 0;
        if (t < 64) xz[t] = 0;
    } else {
        // W96T[n][k]: k<64 -> (node_w @ conv_w0)[k,n]; k==64 -> (node_b @ conv_w0)[n]; else 0
        int n = b - 769;
        colv[t] = cw[t * 256 + n];  // conv_w layer 0 column n
        __syncthreads();
        if (t < 64) {
            float acc = 0.0f;
            for (int j = 0; j < 256; j++) acc += nw[t * 256 + j] * colv[j];
            w96[n * 96 + t] = f2bf(acc);
        } else if (t == 64) {
            float acc = 0.0f;
            for (int j = 0; j < 256; j++) acc += nb[j] * colv[j];
            w96[n * 96 + t] = f2bf(acc);
        } else if (t < 96) {
            w96[n * 96 + t] = 0;
        }
    }
}

// ---------------- degree / CSR build ----------------

__global__ void deg_kernel(const int* __restrict__ col, int* __restrict__ cnt, int E) {
    int e = blockIdx.x * 256 + threadIdx.x;
    if (e < E) atomicAdd(&cnt[col[e]], 1);
}

__global__ void scan1_kernel(const int* __restrict__ cnt, int* __restrict__ scanbuf,
                             int* __restrict__ bsum, float* __restrict__ dis, int N) {
    __shared__ int s[512];
    int i = blockIdx.x * 512 + threadIdx.x;
    int c = (i < N) ? cnt[i] : 0;
    if (i < N) dis[i] = rsqrtf((float)c + 1.0f);  // +1 self-loop
    s[threadIdx.x] = c;
    __syncthreads();
    for (int off = 1; off < 512; off <<= 1) {
        int t = (threadIdx.x >= off) ? s[threadIdx.x - off] : 0;
        __syncthreads();
        s[threadIdx.x] += t;
        __syncthreads();
    }
    if (i < N) scanbuf[i] = s[threadIdx.x];
    if (threadIdx.x == 511) bsum[blockIdx.x] = s[511];
}

__global__ void scan2_kernel(const int* __restrict__ bsum, int* __restrict__ boff, int nb) {
    __shared__ int s[128];
    int t = threadIdx.x;
    int v = (t < nb) ? bsum[t] : 0;
    s[t] = v;
    __syncthreads();
    for (int off = 1; off < 128; off <<= 1) {
        int u = (t >= off) ? s[t - off] : 0;
        __syncthreads();
        s[t] += u;
        __syncthreads();
    }
    if (t < nb) boff[t] = s[t] - v;  // exclusive
}

__global__ void scan3_kernel(const int* __restrict__ scanbuf, const int* __restrict__ boff,
                             int* __restrict__ rowstart, int N) {
    int i = blockIdx.x * 256 + threadIdx.x;
    if (i < N) rowstart[i + 1] = scanbuf[i] + boff[i >> 9];
    if (i == 0) rowstart[0] = 0;
}

// scatter edges into CSR (atomicSub on warm cnt; counts dead after scan);
// also accumulate sdis[v] = sum of dis[src] over in-edges
__global__ void scatter_kernel(const int* __restrict__ row, const int* __restrict__ col,
                               const int* __restrict__ rowstart, int* __restrict__ cnt,
                               int* __restrict__ eidx, const float* __restrict__ dis,
                               float* __restrict__ sdis, int E) {
    int e = blockIdx.x * 256 + threadIdx.x;
    if (e < E) {
        int c = col[e];
        int r = row[e];
        int old = atomicSub(&cnt[c], 1);
        eidx[rowstart[c] + old - 1] = r;
        atomicAdd(&sdis[c], dis[r]);
    }
}

// xs[u] = dis[u] * x[u]  (bf16, N x 64)
__global__ void xs_kernel(const float* __restrict__ x, const float* __restrict__ dis,
                          unsigned short* __restrict__ xs, int total4) {
    int i4 = blockIdx.x * 256 + threadIdx.x;
    if (i4 < total4) {
        int i = i4 * 4;
        float d = dis[i >> 6];
        float4 v = *reinterpret_cast<const float4*>(x + i);
        *reinterpret_cast<uint2*>(xs + i) = pack4(d * v.x, d * v.y, d * v.z, d * v.w);
    }
}

// ---------------- GEMM (m97 recipe): C[M,Nc] = A[M,K] * BT[Nc,K]^T ----------------
// bf16 in, fp32 MFMA accumulate, bf16 out; optional per-row scale[mr];
// stats_accum: accumulate per-column sum/sumsq of C into stats (layer-1 BN);
// stats_clear: zero stats[512] (block 0,0) for the NEXT layer's agg.

__global__ __launch_bounds__(256)
void gemm_bt_kernel(const unsigned short* __restrict__ A, const unsigned short* __restrict__ BT,
                    unsigned short* __restrict__ C, const float* __restrict__ scale,
                    float* __restrict__ stats_accum, float* __restrict__ stats_clear,
                    int M, int K, int Nc) {
    __shared__ unsigned short As[128 * 32];
    __shared__ unsigned short Bs[128 * 32];
    __shared__ float stLS[256];

    if (stats_clear && blockIdx.x == 0 && blockIdx.y == 0) {
        stats_clear[threadIdx.x] = 0.0f;
        stats_clear[256 + threadIdx.x] = 0.0f;
    }
    if (stats_accum) stLS[threadIdx.x] = 0.0f;

    const int lane = threadIdx.x & 63;
    const int wave = threadIdx.x >> 6;
    const int wm = wave >> 1, wn = wave & 1;
    const int r = lane & 15, q = lane >> 4;
    const int m0b = blockIdx.x * 128;
    const int n0b = blockIdx.y * 128;
    const int m0 = m0b + wm * 64;
    const int n0 = n0b + wn * 64;

    f32x4 acc[4][4] = {};

    for (int k0 = 0; k0 < K; k0 += 32) {
        __syncthreads();  // previous tile consumed
#pragma unroll
        for (int j = 0; j < 2; j++) {
            int s = threadIdx.x + j * 256;        // 512 slots of 16 B
            int row = s >> 2, kp = s & 3;
            int mr = m0b + row;
            if (mr >= M) mr = M - 1;
            const unsigned short* ga = A + (size_t)mr * K + k0 + kp * 8;
            __builtin_amdgcn_global_load_lds((const AS1 void*)ga, (AS3 void*)(As + s * 8), 16, 0, 0);
            int nr = n0b + row;                    // Nc is a multiple of 128
            const unsigned short* gb = BT + (size_t)nr * K + k0 + kp * 8;
            __builtin_amdgcn_global_load_lds((const AS1 void*)gb, (AS3 void*)(Bs + s * 8), 16, 0, 0);
        }
        __syncthreads();  // drains vmcnt -> LDS ready

        bf16x8 a[4], b[4];
#pragma unroll
        for (int i = 0; i < 4; i++)
            a[i] = *reinterpret_cast<const bf16x8*>(As + ((wm * 64 + i * 16 + r) * 32 + q * 8));
#pragma unroll
        for (int j = 0; j < 4; j++)
            b[j] = *reinterpret_cast<const bf16x8*>(Bs + ((wn * 64 + j * 16 + r) * 32 + q * 8));
#pragma unroll
        for (int i = 0; i < 4; i++)
#pragma unroll
            for (int j = 0; j < 4; j++)
                acc[i][j] = __builtin_amdgcn_mfma_f32_16x16x32_bf16(a[i], b[j], acc[i][j], 0, 0, 0);
    }

    float psl[4] = {}, pql[4] = {};
#pragma unroll
    for (int i = 0; i < 4; i++) {
#pragma unroll
        for (int t = 0; t < 4; t++) {
            int mr = m0 + i * 16 + q * 4 + t;  // C/D: row = q*4+reg, col = lane&15
            if (mr < M) {
                float rs = scale ? scale[mr] : 1.0f;
#pragma unroll
                for (int j = 0; j < 4; j++) {
                    int nc = n0 + j * 16 + r;
                    float v = acc[i][j][t] * rs;
                    C[(size_t)mr * Nc + nc] = f2bf(v);
                    psl[j] += v;
                    pql[j] += v * v;
                }
            }
        }
    }

    if (stats_accum) {
        __syncthreads();  // stLS zeroed by all threads
#pragma unroll
        for (int j = 0; j < 4; j++) {
            int c = wn * 64 + j * 16 + r;
            atomicAdd(&stLS[c], psl[j]);
            atomicAdd(&stLS[128 + c], pql[j]);
        }
        __syncthreads();
        if (threadIdx.x < 128) {
            atomicAdd(&stats_accum[n0b + threadIdx.x], stLS[threadIdx.x]);
            atomicAdd(&stats_accum[256 + n0b + threadIdx.x], stLS[128 + threadIdx.x]);
        }
    }
}

// ---------------- aggx: layer-1 aggregation over xs (64 feats) -> y96 ----------------
// Triple-buffered; y row = [ dis_v*(xs_v + sum xs_src) (64) | s_v (1) | 0 pad to 96 ].

__global__ __launch_bounds__(256)
void aggx_kernel(const unsigned short* __restrict__ xs, const int* __restrict__ rowstart,
                 const int* __restrict__ eidx, const float* __restrict__ dis,
                 const float* __restrict__ sdis, unsigned short* __restrict__ y96, int N) {
    const int lane = threadIdx.x & 63;
    const int wave = threadIdx.x >> 6;
    const int slot = lane >> 3;       // 8 edges per round
    const int fl = (lane & 7) * 8;    // 8 features per lane

    const int vb = __builtin_amdgcn_readfirstlane(blockIdx.x * 16 + wave * 4);

    int rs[5];
#pragma unroll
    for (int s = 0; s < 5; s++) rs[s] = rowstart[min(vb + s, N)];
    int js[4], de[4];
    float dvv[4], svv[4];
#pragma unroll
    for (int s = 0; s < 4; s++) {
        js[s] = rs[s];
        bool ok = (vb + s) < N;
        de[s] = ok ? (rs[s + 1] - rs[s]) : 0;
        float dv = ok ? dis[vb + s] : 0.0f;
        dvv[s] = dv;
        svv[s] = ok ? (dv * (dv + sdis[vb + s])) : 0.0f;
    }

    int idx0 = (lane < de[0]) ? eidx[js[0] + lane] : N;
    int idx1 = (lane < de[1]) ? eidx[js[1] + lane] : N;
    int idx2 = (lane < de[2]) ? eidx[js[2] + lane] : N;
    int idx3 = (lane < de[3]) ? eidx[js[3] + lane] : N;

    uint4 sf[4];
#pragma unroll
    for (int s = 0; s < 4; s++)
        sf[s] = *reinterpret_cast<const uint4*>(xs + (size_t)min(vb + s, N) * 64 + fl);

    uint4 rA[2], rB[2], rC[2];

    auto issue = [&](int myidx, uint4 (&rr)[2]) {
#pragma unroll
        for (int ro = 0; ro < 2; ro++) {
            int u = __shfl(myidx, ro * 8 + slot);
            rr[ro] = *reinterpret_cast<const uint4*>(xs + (size_t)u * 64 + fl);
        }
    };

    auto consume = [&](int s, int js_s, int d, float dv, float sv, int myidx, uint4 (&rr)[2]) {
        float a[8] = {};
#pragma unroll
        for (int ro = 0; ro < 2; ro++) {
            float x0, x1, x2, x3;
            unpack4(make_uint2(rr[ro].x, rr[ro].y), x0, x1, x2, x3);
            a[0] += x0; a[1] += x1; a[2] += x2; a[3] += x3;
            unpack4(make_uint2(rr[ro].z, rr[ro].w), x0, x1, x2, x3);
            a[4] += x0; a[5] += x1; a[6] += x2; a[7] += x3;
        }
        int cnp = min(64, (d + 15) & ~15);
        for (int t = 16; t < cnp; t += 16) {
#pragma unroll
            for (int ro = 0; ro < 2; ro++) {
                int u = __shfl(myidx, t + ro * 8 + slot);
                rr[ro] = *reinterpret_cast<const uint4*>(xs + (size_t)u * 64 + fl);
            }
#pragma unroll
            for (int ro = 0; ro < 2; ro++) {
                float x0, x1, x2, x3;
                unpack4(make_uint2(rr[ro].x, rr[ro].y), x0, x1, x2, x3);
                a[0] += x0; a[1] += x1; a[2] += x2; a[3] += x3;
                unpack4(make_uint2(rr[ro].z, rr[ro].w), x0, x1, x2, x3);
                a[4] += x0; a[5] += x1; a[6] += x2; a[7] += x3;
            }
        }
        for (int base = 64; base < d; base += 64) {
            int mi = (base + lane < d) ? eidx[js_s + base + lane] : N;
            int cn2 = min(64, d - base);
            int cnp2 = (cn2 + 15) & ~15;
            for (int t = 0; t < cnp2; t += 16) {
#pragma unroll
                for (int ro = 0; ro < 2; ro++) {
                    int u = __shfl(mi, t + ro * 8 + slot);
                    rr[ro] = *reinterpret_cast<const uint4*>(xs + (size_t)u * 64 + fl);
                }
#pragma unroll
                for (int ro = 0; ro < 2; ro++) {
                    float x0, x1, x2, x3;
                    unpack4(make_uint2(rr[ro].x, rr[ro].y), x0, x1, x2, x3);
                    a[0] += x0; a[1] += x1; a[2] += x2; a[3] += x3;
                    unpack4(make_uint2(rr[ro].z, rr[ro].w), x0, x1, x2, x3);
                    a[4] += x0; a[5] += x1; a[6] += x2; a[7] += x3;
                }
            }
        }
#pragma unroll
        for (int j = 0; j < 8; j++) {
            a[j] += __shfl_xor(a[j], 8);
            a[j] += __shfl_xor(a[j], 16);
            a[j] += __shfl_xor(a[j], 32);
        }
        if ((vb + s) < N) {
            if (lane < 8) {
                float x0, x1, x2, x3;
                unpack4(make_uint2(sf[s].x, sf[s].y), x0, x1, x2, x3);
                a[0] += x0; a[1] += x1; a[2] += x2; a[3] += x3;
                unpack4(make_uint2(sf[s].z, sf[s].w), x0, x1, x2, x3);
                a[4] += x0; a[5] += x1; a[6] += x2; a[7] += x3;
                uint2 lo = pack4(dv * a[0], dv * a[1], dv * a[2], dv * a[3]);
                uint2 hi = pack4(dv * a[4], dv * a[5], dv * a[6], dv * a[7]);
                *reinterpret_cast<uint4*>(y96 + (size_t)(vb + s) * 96 + fl) =
                    make_uint4(lo.x, lo.y, hi.x, hi.y);
            } else if (lane < 12) {
                unsigned sx = (lane == 8) ? (unsigned)f2bf(sv) : 0u;
                *reinterpret_cast<uint4*>(y96 + (size_t)(vb + s) * 96 + 64 + (lane - 8) * 8) =
                    make_uint4(sx, 0u, 0u, 0u);
            }
        }
    };

    issue(idx0, rA);
    issue(idx1, rB);
    issue(idx2, rC);
    consume(0, js[0], de[0], dvv[0], svv[0], idx0, rA);
    issue(idx3, rA);
    consume(1, js[1], de[1], dvv[1], svv[1], idx1, rB);
    consume(2, js[2], de[2], dvv[2], svv[2], idx2, rC);
    consume(3, js[3], de[3], dvv[3], svv[3], idx3, rA);
}

// ---------------- aggregation layers 2-3: R4 ping-pong, TRIPLE-buffered + fused BN stats ----------------
// conv_b dropped (BatchNorm cancels per-feature constants exactly).
// 3 in-flight node buffers: 24 gather loads outstanding at startup vs 16.

__global__ __launch_bounds__(256)
void agg_kernel(const unsigned short* __restrict__ hws, const int* __restrict__ rowstart,
                const int* __restrict__ eidx, const float* __restrict__ dis,
                unsigned short* __restrict__ agg, float* __restrict__ stats, int N) {
    __shared__ float s_sum[4][256];
    __shared__ float s_sq[4][256];
    const int lane = threadIdx.x & 63;
    const int wave = threadIdx.x >> 6;
    const int sub = lane >> 5;         // edge parity
    const int fl = (lane & 31) * 8;    // feature base (8 features per lane)

    const int vb = __builtin_amdgcn_readfirstlane(blockIdx.x * 16 + wave * 4);

    int rs[5];
#pragma unroll
    for (int s = 0; s < 5; s++) rs[s] = rowstart[min(vb + s, N)];
    int js[4], de[4];
    float dvv[4];
#pragma unroll
    for (int s = 0; s < 4; s++) {
        js[s] = rs[s];
        de[s] = (vb + s < N) ? (rs[s + 1] - rs[s]) : 0;
        dvv[s] = (vb + s < N) ? dis[vb + s] : 0.0f;
    }

    int idx0 = (lane < de[0]) ? eidx[js[0] + lane] : N;
    int idx1 = (lane < de[1]) ? eidx[js[1] + lane] : N;
    int idx2 = (lane < de[2]) ? eidx[js[2] + lane] : N;
    int idx3 = (lane < de[3]) ? eidx[js[3] + lane] : N;
    uint4 sf[4];
#pragma unroll
    for (int s = 0; s < 4; s++)
        sf[s] = *reinterpret_cast<const uint4*>(hws + (size_t)min(vb + s, N) * 256 + fl);

    float ps[8] = {}, pq[8] = {};

    uint4 rA[8], rB[8], rC[8];

    auto issue = [&](int myidx, uint4 (&rr)[8]) {
#pragma unroll
        for (int k = 0; k < 8; k++) {
            int u = __shfl(myidx, 2 * k + sub);
            rr[k] = *reinterpret_cast<const uint4*>(hws + (size_t)u * 256 + fl);
        }
    };

    auto consume = [&](int s, int js_s, int d, float dvs, int myidx, uint4 (&rr)[8]) {
        float a[8] = {};
#pragma unroll
        for (int k = 0; k < 8; k++) {
            float x0, x1, x2, x3;
            unpack4(make_uint2(rr[k].x, rr[k].y), x0, x1, x2, x3);
            a[0] += x0; a[1] += x1; a[2] += x2; a[3] += x3;
            unpack4(make_uint2(rr[k].z, rr[k].w), x0, x1, x2, x3);
            a[4] += x0; a[5] += x1; a[6] += x2; a[7] += x3;
        }
        int cnp = min(64, (d + 15) & ~15);
        for (int t = 16; t < cnp; t += 16) {
#pragma unroll
            for (int k = 0; k < 8; k++) {
                int u = __shfl(myidx, t + 2 * k + sub);
                rr[k] = *reinterpret_cast<const uint4*>(hws + (size_t)u * 256 + fl);
            }
#pragma unroll
            for (int k = 0; k < 8; k++) {
                float x0, x1, x2, x3;
                unpack4(make_uint2(rr[k].x, rr[k].y), x0, x1, x2, x3);
                a[0] += x0; a[1] += x1; a[2] += x2; a[3] += x3;
                unpack4(make_uint2(rr[k].z, rr[k].w), x0, x1, x2, x3);
                a[4] += x0; a[5] += x1; a[6] += x2; a[7] += x3;
            }
        }
        for (int base = 64; base < d; base += 64) {
            int mi = (base + lane < d) ? eidx[js_s + base + lane] : N;
            int cn2 = min(64, d - base);
            int cnp2 = (cn2 + 15) & ~15;
            for (int t = 0; t < cnp2; t += 16) {
#pragma unroll
                for (int k = 0; k < 8; k++) {
                    int u = __shfl(mi, t + 2 * k + sub);
                    rr[k] = *reinterpret_cast<const uint4*>(hws + (size_t)u * 256 + fl);
                }
#pragma unroll
                for (int k = 0; k < 8; k++) {
                    float x0, x1, x2, x3;
                    unpack4(make_uint2(rr[k].x, rr[k].y), x0, x1, x2, x3);
                    a[0] += x0; a[1] += x1; a[2] += x2; a[3] += x3;
                    unpack4(make_uint2(rr[k].z, rr[k].w), x0, x1, x2, x3);
                    a[4] += x0; a[5] += x1; a[6] += x2; a[7] += x3;
                }
            }
        }
#pragma unroll
        for (int j = 0; j < 8; j++) a[j] += __shfl_xor(a[j], 32);
        float x0, x1, x2, x3;
        unpack4(make_uint2(sf[s].x, sf[s].y), x0, x1, x2, x3);
        a[0] += x0; a[1] += x1; a[2] += x2; a[3] += x3;
        unpack4(make_uint2(sf[s].z, sf[s].w), x0, x1, x2, x3);
        a[4] += x0; a[5] += x1; a[6] += x2; a[7] += x3;
        float g[8];
#pragma unroll
        for (int j = 0; j < 8; j++) g[j] = dvs * a[j];
        if (vb + s < N && sub == 0) {
            uint2 lo = pack4(g[0], g[1], g[2], g[3]);
            uint2 hi = pack4(g[4], g[5], g[6], g[7]);
            *reinterpret_cast<uint4*>(agg + (size_t)(vb + s) * 256 + fl) =
                make_uint4(lo.x, lo.y, hi.x, hi.y);
#pragma unroll
            for (int j = 0; j < 8; j++) { ps[j] += g[j]; pq[j] += g[j] * g[j]; }
        }
    };

    issue(idx0, rA);
    issue(idx1, rB);
    issue(idx2, rC);
    consume(0, js[0], de[0], dvv[0], idx0, rA);
    issue(idx3, rA);
    consume(1, js[1], de[1], dvv[1], idx1, rB);
    consume(2, js[2], de[2], dvv[2], idx2, rC);
    consume(3, js[3], de[3], dvv[3], idx3, rA);

    if (sub == 0) {
#pragma unroll
        for (int j = 0; j < 8; j++) {
            s_sum[wave][fl + j] = ps[j];
            s_sq[wave][fl + j] = pq[j];
        }
    }
    __syncthreads();

    int f = threadIdx.x;
    float ts = s_sum[0][f] + s_sum[1][f] + s_sum[2][f] + s_sum[3][f];
    float tq = s_sq[0][f] + s_sq[1][f] + s_sq[2][f] + s_sq[3][f];
    atomicAdd(&stats[f], ts);
    atomicAdd(&stats[256 + f], tq);
}

// ---------------- elem: BN affine (inline from stats) + ReLU -> bf16 h (layers 1-2) ----------------

__global__ __launch_bounds__(256)
void elem_kernel(const unsigned short* __restrict__ agg, const float* __restrict__ stats,
                 const float* __restrict__ bng, const float* __restrict__ bnb,
                 unsigned short* __restrict__ h, float inv_n, size_t total) {
    __shared__ float ssL[512];
    {
        int f = threadIdx.x;
        float mean = stats[f] * inv_n;
        float var = stats[256 + f] * inv_n - mean * mean;
        float sc = bng[f] * rsqrtf(var + 1e-5f);
        ssL[f] = sc;
        ssL[256 + f] = bnb[f] - mean * sc;
    }
    __syncthreads();
    size_t i = ((size_t)blockIdx.x * 256 + threadIdx.x) * 4;
    if (i < total) {
        float a0, a1, a2, a3;
        unpack4(*reinterpret_cast<const uint2*>(agg + i), a0, a1, a2, a3);
        int f = (int)(i & 255);
        float r0 = fmaxf(a0 * ssL[f] + ssL[256 + f], 0.0f);
        float r1 = fmaxf(a1 * ssL[f + 1] + ssL[256 + f + 1], 0.0f);
        float r2 = fmaxf(a2 * ssL[f + 2] + ssL[256 + f + 2], 0.0f);
        float r3 = fmaxf(a3 * ssL[f + 3] + ssL[256 + f + 3], 0.0f);
        *reinterpret_cast<uint2*>(h + i) = pack4(r0, r1, r2, r3);
    }
}

// ---------------- elem_pool: layer-3 BN+ReLU fused directly into global_add_pool ----------------

__global__ __launch_bounds__(256)
void elem_pool_kernel(const unsigned short* __restrict__ agg, const float* __restrict__ stats,
                      const float* __restrict__ bng, const float* __restrict__ bnb,
                      const int* __restrict__ batch, float* __restrict__ g,
                      float inv_n, int N) {
    __shared__ float ssL[512];
    __shared__ int sb[32];
    int f = threadIdx.x;
    {
        float mean = stats[f] * inv_n;
        float var = stats[256 + f] * inv_n - mean * mean;
        float sc = bng[f] * rsqrtf(var + 1e-5f);
        ssL[f] = sc;
        ssL[256 + f] = bnb[f] - mean * sc;
    }
    int r0 = blockIdx.x * 32;
    int rows = min(32, N - r0);
    if (f < 32) sb[f] = (r0 + f < N) ? batch[r0 + f] : -1;
    __syncthreads();
    float sc = ssL[f], sh = ssL[256 + f];
    float acc = 0.0f;
    int cur = sb[0];
    for (int t = 0; t < rows; t++) {
        int b = sb[t];
        if (b != cur) {
            atomicAdd(&g[cur * 256 + f], acc);
            acc = 0.0f;
            cur = b;
        }
        float v = bf2f(agg[(size_t)(r0 + t) * 256 + f]);
        acc += fmaxf(v * sc + sh, 0.0f);
    }
    atomicAdd(&g[cur * 256 + f], acc);
}

// ---------------- head MLP: relu(g@w1+b1)@w2+b2 ----------------

__global__ void head_kernel(const float* __restrict__ g, const float* __restrict__ w1,
                            const float* __restrict__ b1, const float* __restrict__ w2,
                            const float* __restrict__ b2, float* __restrict__ out) {
    __shared__ float gr[256];
    __shared__ float z[128];
    int b = blockIdx.x, t = threadIdx.x;
    gr[t] = g[b * 256 + t];
    gr[t + 128] = g[b * 256 + 128 + t];
    __syncthreads();
    float acc = b1[t];
    for (int k = 0; k < 256; k++) acc += gr[k] * w1[k * 128 + t];
    z[t] = fmaxf(acc, 0.0f);
    __syncthreads();
    if (t < 12) {
        float o = b2[t];
        for (int k = 0; k < 128; k++) o += z[k] * w2[k * 12 + t];
        out[b * 12 + t] = o;
    }
}

// ---------------- launch ----------------

extern "C" void kernel_launch(void* const* d_in, const int* in_sizes, int n_in,
                              void* d_out, int out_size, void* d_ws, size_t ws_size,
                              hipStream_t stream) {
    const float* x      = (const float*)d_in[0];
    const int*   ei     = (const int*)d_in[1];
    const int*   batch  = (const int*)d_in[2];
    const float* node_w = (const float*)d_in[3];
    const float* node_b = (const float*)d_in[4];
    const float* conv_w = (const float*)d_in[5];
    const float* bn_g   = (const float*)d_in[7];
    const float* bn_b   = (const float*)d_in[8];
    const float* hw1    = (const float*)d_in[9];
    const float* hb1    = (const float*)d_in[10];
    const float* hw2    = (const float*)d_in[11];
    const float* hb2    = (const float*)d_in[12];
    float* out = (float*)d_out;

    const int N = in_sizes[2];
    const int E = in_sizes[1] / 2;
    const int H = 256;
    const float inv_n = 1.0f / (float)N;

    char* base = (char*)d_ws;
    size_t off = 0;
    auto alloc = [&](size_t bytes) -> void* {
        off = (off + 255) & ~(size_t)255;
        void* p = base + off;
        off += bytes;
        return p;
    };
    unsigned short* xs  = (unsigned short*)alloc((size_t)(N + 1) * 64 * 2);   // +1 zero row
    unsigned short* y96 = (unsigned short*)alloc((size_t)N * 96 * 2);
    unsigned short* w96 = (unsigned short*)alloc((size_t)256 * 96 * 2);
    unsigned short* h   = (unsigned short*)alloc((size_t)N * H * 2);
    unsigned short* hws = (unsigned short*)alloc((size_t)(N + 1) * H * 2);    // +1 zero row
    unsigned short* agg = (unsigned short*)alloc((size_t)N * H * 2);
    unsigned short* cwT = (unsigned short*)alloc((size_t)3 * H * H * 2);
    // contiguous zero region: cnt | sdis | stats | gpool
    int* zero_region = (int*)alloc(((size_t)2 * N + 512 + 64 * H) * 4);
    int* cnt      = zero_region;
    float* sdis   = (float*)(zero_region + N);
    float* stats  = (float*)(zero_region + 2 * N);
    float* gpool  = (float*)(zero_region + 2 * N + 512);
    int* rowstart = (int*)alloc((size_t)(N + 1) * 4);
    int* scanbuf  = (int*)alloc((size_t)N * 4);
    int* bsum     = (int*)alloc(1024);
    int* boff     = (int*)alloc(1024);
    int* eidx     = (int*)alloc((size_t)(E + 64) * 4);
    float* dis    = (float*)alloc((size_t)N * 4);

    const int* row = ei;
    const int* col = ei + E;

    hipMemsetAsync(zero_region, 0, ((size_t)2 * N + 512 + 64 * H) * 4, stream);

    // cwT transpose + zero pad rows + w96 fuse, one packed grid
    prep_kernel<<<dim3(768 + 1 + 256), 256, 0, stream>>>(
        conv_w, cwT, hws + (size_t)N * H, xs + (size_t)N * 64, node_w, node_b, w96);

    deg_kernel<<<dim3((E + 255) / 256), 256, 0, stream>>>(col, cnt, E);
    int nb = (N + 511) / 512;
    scan1_kernel<<<dim3(nb), 512, 0, stream>>>(cnt, scanbuf, bsum, dis, N);
    scan2_kernel<<<dim3(1), 128, 0, stream>>>(bsum, boff, nb);
    scan3_kernel<<<dim3((N + 255) / 256), 256, 0, stream>>>(scanbuf, boff, rowstart, N);
    scatter_kernel<<<dim3((E + 255) / 256), 256, 0, stream>>>(row, col, rowstart, cnt, eidx,
                                                              dis, sdis, E);
    xs_kernel<<<dim3((N * 64 / 4 + 255) / 256), 256, 0, stream>>>(x, dis, xs, N * 64 / 4);

    dim3 gg((N + 127) / 128, H / 128);
    size_t elem_blocks = ((size_t)N * H / 4 + 255) / 256;

    // layer 1: aggregate xs -> y96; K=96 GEMM with fused BN-stats accumulation
    aggx_kernel<<<dim3((N + 15) / 16), 256, 0, stream>>>(xs, rowstart, eidx, dis, sdis, y96, N);
    gemm_bt_kernel<<<gg, 256, 0, stream>>>(y96, w96, agg, nullptr, stats, nullptr, N, 96, H);
    elem_kernel<<<dim3((int)elem_blocks), 256, 0, stream>>>(agg, stats, bn_g, bn_b, h,
                                                            inv_n, (size_t)N * H);

    // layer 2
    gemm_bt_kernel<<<gg, 256, 0, stream>>>(h, cwT + (size_t)1 * H * H, hws, dis,
                                           nullptr, stats, N, H, H);
    agg_kernel<<<dim3((N + 15) / 16), 256, 0, stream>>>(hws, rowstart, eidx, dis, agg, stats, N);
    elem_kernel<<<dim3((int)elem_blocks), 256, 0, stream>>>(agg, stats, bn_g + H, bn_b + H, h,
                                                            inv_n, (size_t)N * H);

    // layer 3 (elem fused into pool; h never written)
    gemm_bt_kernel<<<gg, 256, 0, stream>>>(h, cwT + (size_t)2 * H * H, hws, dis,
                                           nullptr, stats, N, H, H);
    agg_kernel<<<dim3((N + 15) / 16), 256, 0, stream>>>(hws, rowstart, eidx, dis, agg, stats, N);
    elem_pool_kernel<<<dim3((N + 31) / 32), 256, 0, stream>>>(agg, stats, bn_g + 2 * H,
                                                              bn_b + 2 * H, batch, gpool,
                                                              inv_n, N);

    head_kernel<<<dim3(64), 128, 0, stream>>>(gpool, hw1, hb1, hw2, hb2, out);
}